// Round 1
// baseline (371.979 us; speedup 1.0000x reference)
//
#include <hip/hip_runtime.h>
#include <stdint.h>

#define Bn 4
#define Cn 256
#define Gn 32
#define Nn 4096
#define CGn 8

typedef unsigned short u16;
typedef __attribute__((ext_vector_type(8))) short short8;
typedef __attribute__((ext_vector_type(4))) short short4v;
typedef __attribute__((ext_vector_type(4))) float f32x4;

__device__ __forceinline__ u16 f2bf(float x) {
  uint32_t u = __float_as_uint(x);
  u += 0x7fffu + ((u >> 16) & 1u);
  return (u16)(u >> 16);
}

// async global->LDS, 16B per lane; lds base must be wave-uniform
__device__ __forceinline__ void gl_lds16(const void* g, void* l) {
  __builtin_amdgcn_global_load_lds(
      (__attribute__((address_space(1))) void*)(uintptr_t)g,
      (__attribute__((address_space(3))) void*)(uintptr_t)l, 16, 0, 0);
}

// XOR-swizzled tile addressing: rows of 512B (32 x 16B chunks) / 128B (8 chunks).
// physical chunk = logical chunk ^ (row & 7)  (involution)
__device__ __forceinline__ int sw512(int row, int cb) { return row * 512 + ((cb ^ (row & 7)) * 16); }
__device__ __forceinline__ int sw128(int row, int cb) { return row * 128 + ((cb ^ (row & 7)) * 16); }

// ---------------- weight convert: fp32 -> bf16, fold log2(e)/16 into wq,bq ----
__global__ void k_conv(const float* __restrict__ wq, const float* __restrict__ wk,
                       const float* __restrict__ wv, const float* __restrict__ wp,
                       const float* __restrict__ bq, const float* __restrict__ bk,
                       const float* __restrict__ bv,
                       u16* __restrict__ wqkv, u16* __restrict__ wpb, float* __restrict__ bqkv) {
  const float s = 0.09016844005556021f;  // log2(e) / sqrt(256)
  int i = blockIdx.x * 256 + threadIdx.x;  // grid 256 -> 65536 threads
  wqkv[i]          = f2bf(wq[i] * s);
  wqkv[i + 65536]  = f2bf(wk[i]);
  wqkv[i + 131072] = f2bf(wv[i]);
  wpb[i]           = f2bf(wp[i]);
  if (i < 256) { bqkv[i] = bq[i] * s; bqkv[i + 256] = bk[i]; bqkv[i + 512] = bv[i]; }
}

// ---------------- GroupNorm stats: one block per (b,g), 8ch x 4096 contiguous --
__global__ void k_stats(const float* __restrict__ x, float* __restrict__ stats) {
  int blk = blockIdx.x;  // b*32+g
  const float4* base = (const float4*)(x + (size_t)blk * (CGn * Nn));
  float s = 0.f, s2 = 0.f;
  for (int i = threadIdx.x; i < (CGn * Nn) / 4; i += 256) {
    float4 v = base[i];
    s  += v.x + v.y + v.z + v.w;
    s2 += v.x * v.x + v.y * v.y + v.z * v.z + v.w * v.w;
  }
#pragma unroll
  for (int m = 1; m < 64; m <<= 1) { s += __shfl_xor(s, m, 64); s2 += __shfl_xor(s2, m, 64); }
  __shared__ float ps[4], ps2[4];
  int w = threadIdx.x >> 6;
  if ((threadIdx.x & 63) == 0) { ps[w] = s; ps2[w] = s2; }
  __syncthreads();
  if (threadIdx.x == 0) {
    float S = ps[0] + ps[1] + ps[2] + ps[3];
    float S2 = ps2[0] + ps2[1] + ps2[2] + ps2[3];
    const float inv = 1.f / (CGn * Nn);
    float mu = S * inv;
    float var = S2 * inv - mu * mu;
    stats[blk * 2] = mu;
    stats[blk * 2 + 1] = rsqrtf(var + 1e-6f);
  }
}

// ---------------- GN apply -> hnT (N,C) bf16 ---------------------------------
__global__ void k_apply(const float* __restrict__ x, const float* __restrict__ stats,
                        const float* __restrict__ gsc, const float* __restrict__ gbi,
                        u16* __restrict__ hnT) {
  int n0 = blockIdx.x * 64;
  int b = blockIdx.y;
  int tid = threadIdx.x;
  __shared__ float smu[Gn], srs[Gn];
  if (tid < Gn) { smu[tid] = stats[(b * Gn + tid) * 2]; srs[tid] = stats[(b * Gn + tid) * 2 + 1]; }
  __syncthreads();
  int nl = (tid & 15) * 4;
  int cbase = tid >> 4;
  for (int pass = 0; pass < 16; ++pass) {
    int c = pass * 16 + cbase;
    float4 v = *(const float4*)(x + (size_t)b * Cn * Nn + (size_t)c * Nn + n0 + nl);
    int g = c >> 3;
    float sc = gsc[c] * srs[g];
    float bi = gbi[c] - smu[g] * sc;
    u16* dst = hnT + (size_t)b * Nn * Cn + (size_t)(n0 + nl) * Cn + c;
    dst[0]      = f2bf(v.x * sc + bi);
    dst[Cn]     = f2bf(v.y * sc + bi);
    dst[2 * Cn] = f2bf(v.z * sc + bi);
    dst[3 * Cn] = f2bf(v.w * sc + bi);
  }
}

// ---------------- fused QKV GEMM: out[d,n] = sum_c W[d,c] hn[c,n] + bias ------
// q,k stored transposed (N,C); v stored (C,N)
__global__ __launch_bounds__(256, 2)
void k_qkv(const u16* __restrict__ wqkv, const float* __restrict__ bqkv,
           const u16* __restrict__ hnT, u16* __restrict__ qT, u16* __restrict__ kT,
           u16* __restrict__ vv) {
  __shared__ __align__(16) char smem[65536];  // Ws [64][512B sw] | hns [64][512B sw]
  int tid = threadIdx.x, lane = tid & 63, w = tid >> 6, quad = lane >> 4, low = lane & 15;
  int n0 = blockIdx.x * 64, d0 = blockIdx.y * 64, b = blockIdx.z;
  {
    int r0 = w * 16;
#pragma unroll
    for (int s = 0; s < 8; ++s) {
      int rs = r0 + s * 2;
      int r = rs + (lane >> 5);
      int cb = (lane & 31) ^ (r & 7);
      gl_lds16(wqkv + (size_t)(d0 + r) * Cn + cb * 8, smem + rs * 512);
      gl_lds16(hnT + ((size_t)b * Nn + n0 + r) * Cn + cb * 8, smem + 32768 + rs * 512);
    }
  }
  asm volatile("s_waitcnt vmcnt(0)" ::: "memory");
  __syncthreads();
  f32x4 acc[4] = {{0.f,0.f,0.f,0.f},{0.f,0.f,0.f,0.f},{0.f,0.f,0.f,0.f},{0.f,0.f,0.f,0.f}};
#pragma unroll
  for (int kk = 0; kk < 8; ++kk) {
    short8 af = *(const short8*)(smem + sw512(w * 16 + low, kk * 4 + quad));
#pragma unroll
    for (int t = 0; t < 4; ++t) {
      short8 bf = *(const short8*)(smem + 32768 + sw512(t * 16 + low, kk * 4 + quad));
      acc[t] = __builtin_amdgcn_mfma_f32_16x16x32_bf16(af, bf, acc[t], 0, 0, 0);
    }
  }
  int which = d0 >> 8;
  int dloc = (d0 & 255) + w * 16 + quad * 4;
  float bias[4];
#pragma unroll
  for (int r = 0; r < 4; ++r) bias[r] = bqkv[d0 + w * 16 + quad * 4 + r];
  if (which == 2) {
    u16* vp = vv + (size_t)b * Cn * Nn;
#pragma unroll
    for (int t = 0; t < 4; ++t)
#pragma unroll
      for (int r = 0; r < 4; ++r)
        vp[(size_t)(dloc + r) * Nn + n0 + t * 16 + low] = f2bf(acc[t][r] + bias[r]);
  } else {
    u16* dst = (which == 0 ? qT : kT) + (size_t)b * Nn * Cn;
#pragma unroll
    for (int t = 0; t < 4; ++t) {
      short4v pk;
#pragma unroll
      for (int r = 0; r < 4; ++r) pk[r] = (short)f2bf(acc[t][r] + bias[r]);
      *(short4v*)(dst + (size_t)(n0 + t * 16 + low) * Cn + dloc) = pk;
    }
  }
}

// ---------------- flash attention: per block 64 q-rows, stream 64-col kv tiles
__global__ __launch_bounds__(256, 1)
void k_flash(const u16* __restrict__ qT, const u16* __restrict__ kT,
             const u16* __restrict__ vv, u16* __restrict__ OT) {
  __shared__ __align__(16) char smem[65536];  // ks [64][512B sw] | vs [256][128B sw]
  const int tid = threadIdx.x, lane = tid & 63, w = tid >> 6, quad = lane >> 4, low = lane & 15;
  const int b = blockIdx.x >> 6;
  const int i0 = (blockIdx.x & 63) * 64;
  const u16* qTb = qT + (size_t)b * Nn * Cn;
  const u16* kTb = kT + (size_t)b * Nn * Cn;
  const u16* vb  = vv + (size_t)b * Cn * Nn;

  // q A-fragments for this wave's 16 rows, held in registers (full K=256)
  short8 qf[8];
  {
    const u16* qrow = qTb + (size_t)(i0 + w * 16 + low) * Cn;
#pragma unroll
    for (int kk = 0; kk < 8; ++kk) qf[kk] = *(const short8*)(qrow + kk * 32 + quad * 8);
  }
  f32x4 O[16];
#pragma unroll
  for (int t = 0; t < 16; ++t) O[t] = (f32x4){0.f, 0.f, 0.f, 0.f};
  float m_[4], l_[4];
#pragma unroll
  for (int r = 0; r < 4; ++r) { m_[r] = -1e30f; l_[r] = 0.f; }

  for (int jt = 0; jt < 64; ++jt) {
    const int j0 = jt * 64;
    __syncthreads();  // everyone done reading prev ks/vs/P
    {
      int r0 = w * 16;
#pragma unroll
      for (int s = 0; s < 8; ++s) {  // ks: 64 rows x 512B from kT rows j0+r
        int rs = r0 + s * 2;
        int r = rs + (lane >> 5);
        int cb = (lane & 31) ^ (r & 7);
        gl_lds16(kTb + (size_t)(j0 + r) * Cn + cb * 8, smem + rs * 512);
      }
      int c0 = w * 64;
#pragma unroll
      for (int s = 0; s < 8; ++s) {  // vs: 256 rows x 128B from v rows, col j0
        int rs = c0 + s * 8;
        int r = rs + (lane >> 3);
        int cb = (lane & 7) ^ (r & 7);
        gl_lds16(vb + (size_t)r * Nn + j0 + cb * 8, smem + 32768 + rs * 128);
      }
    }
    asm volatile("s_waitcnt vmcnt(0)" ::: "memory");
    __syncthreads();

    // S = q^T k  (wave: 16 rows x 64 cols, log2-domain logits)
    f32x4 S4[4] = {{0.f,0.f,0.f,0.f},{0.f,0.f,0.f,0.f},{0.f,0.f,0.f,0.f},{0.f,0.f,0.f,0.f}};
#pragma unroll
    for (int kk = 0; kk < 8; ++kk) {
#pragma unroll
      for (int t = 0; t < 4; ++t) {
        short8 bf = *(const short8*)(smem + sw512(t * 16 + low, kk * 4 + quad));
        S4[t] = __builtin_amdgcn_mfma_f32_16x16x32_bf16(qf[kk], bf, S4[t], 0, 0, 0);
      }
    }
    __syncthreads();  // all waves done reading ks; safe to reuse ks region for P

    // online softmax; rows r: global row = i0 + w*16 + quad*4 + r
    float alpha[4];
#pragma unroll
    for (int r = 0; r < 4; ++r) {
      float v0 = fmaxf(fmaxf(S4[0][r], S4[1][r]), fmaxf(S4[2][r], S4[3][r]));
#pragma unroll
      for (int msk = 1; msk < 16; msk <<= 1) v0 = fmaxf(v0, __shfl_xor(v0, msk, 64));
      float mn = fmaxf(m_[r], v0);
      alpha[r] = __builtin_amdgcn_exp2f(m_[r] - mn);
      m_[r] = mn;
    }
    float Pv[4][4], rsum[4] = {0.f, 0.f, 0.f, 0.f};
#pragma unroll
    for (int t = 0; t < 4; ++t)
#pragma unroll
      for (int r = 0; r < 4; ++r) {
        float p = __builtin_amdgcn_exp2f(S4[t][r] - m_[r]);
        Pv[t][r] = p;
        rsum[r] += p;
      }
#pragma unroll
    for (int r = 0; r < 4; ++r) {
      float s0 = rsum[r];
#pragma unroll
      for (int msk = 1; msk < 16; msk <<= 1) s0 += __shfl_xor(s0, msk, 64);
      l_[r] = l_[r] * alpha[r] + s0;
    }
#pragma unroll
    for (int t = 0; t < 16; ++t)
#pragma unroll
      for (int r = 0; r < 4; ++r) O[t][r] *= alpha[r];
    // write P (16 x 64 bf16) to this wave's quarter of the ks region
#pragma unroll
    for (int t = 0; t < 4; ++t)
#pragma unroll
      for (int r = 0; r < 4; ++r) {
        int mrow = quad * 4 + r;
        int col = t * 16 + low;
        int off = w * 8192 + mrow * 128 + (((col >> 3) ^ (mrow & 7)) * 16) + (col & 7) * 2;
        *(u16*)(smem + off) = f2bf(Pv[t][r]);
      }
    // O += P @ V^T
#pragma unroll
    for (int kk2 = 0; kk2 < 2; ++kk2) {
      short8 af = *(const short8*)(smem + w * 8192 + sw128(low, kk2 * 4 + quad));
#pragma unroll
      for (int t = 0; t < 16; ++t) {
        short8 bf = *(const short8*)(smem + 32768 + sw128(t * 16 + low, kk2 * 4 + quad));
        O[t] = __builtin_amdgcn_mfma_f32_16x16x32_bf16(af, bf, O[t], 0, 0, 0);
      }
    }
  }

  __syncthreads();
  // epilogue: O/l -> bf16, transpose via wave-private LDS, store OT (N,C) rows
  float rl[4];
#pragma unroll
  for (int r = 0; r < 4; ++r) rl[r] = __builtin_amdgcn_rcpf(l_[r]);
#pragma unroll
  for (int t = 0; t < 16; ++t)
#pragma unroll
    for (int r = 0; r < 4; ++r) {
      int mrow = quad * 4 + r;
      int col = t * 16 + low;
      int off = w * 8192 + mrow * 512 + (((col >> 3) ^ (mrow & 7)) * 16) + (col & 7) * 2;
      *(u16*)(smem + off) = f2bf(O[t][r] * rl[r]);
    }
  u16* OTb = OT + (size_t)b * Nn * Cn + (size_t)(i0 + w * 16) * Cn;
#pragma unroll
  for (int s = 0; s < 8; ++s) {
    int r = s * 2 + (lane >> 5);
    int pc = lane & 31;
    int cb = pc ^ (r & 7);
    short8 v8 = *(const short8*)(smem + w * 8192 + r * 512 + pc * 16);
    *(short8*)(OTb + (size_t)r * Cn + cb * 8) = v8;
  }
}

// ---------------- proj GEMM + bias + residual --------------------------------
__global__ __launch_bounds__(256, 2)
void k_proj(const u16* __restrict__ wpb, const float* __restrict__ bp,
            const u16* __restrict__ OT, const float* __restrict__ x,
            float* __restrict__ out) {
  __shared__ __align__(16) char smem[65536];
  int tid = threadIdx.x, lane = tid & 63, w = tid >> 6, quad = lane >> 4, low = lane & 15;
  int n0 = blockIdx.x * 64, d0 = blockIdx.y * 64, b = blockIdx.z;
  {
    int r0 = w * 16;
#pragma unroll
    for (int s = 0; s < 8; ++s) {
      int rs = r0 + s * 2;
      int r = rs + (lane >> 5);
      int cb = (lane & 31) ^ (r & 7);
      gl_lds16(wpb + (size_t)(d0 + r) * Cn + cb * 8, smem + rs * 512);
      gl_lds16(OT + ((size_t)b * Nn + n0 + r) * Cn + cb * 8, smem + 32768 + rs * 512);
    }
  }
  asm volatile("s_waitcnt vmcnt(0)" ::: "memory");
  __syncthreads();
  f32x4 acc[4] = {{0.f,0.f,0.f,0.f},{0.f,0.f,0.f,0.f},{0.f,0.f,0.f,0.f},{0.f,0.f,0.f,0.f}};
#pragma unroll
  for (int kk = 0; kk < 8; ++kk) {
    short8 af = *(const short8*)(smem + sw512(w * 16 + low, kk * 4 + quad));
#pragma unroll
    for (int t = 0; t < 4; ++t) {
      short8 bf = *(const short8*)(smem + 32768 + sw512(t * 16 + low, kk * 4 + quad));
      acc[t] = __builtin_amdgcn_mfma_f32_16x16x32_bf16(af, bf, acc[t], 0, 0, 0);
    }
  }
  int dloc = d0 + w * 16 + quad * 4;
#pragma unroll
  for (int t = 0; t < 4; ++t)
#pragma unroll
    for (int r = 0; r < 4; ++r) {
      size_t idx = (size_t)b * Cn * Nn + (size_t)(dloc + r) * Nn + n0 + t * 16 + low;
      out[idx] = x[idx] + acc[t][r] + bp[dloc + r];
    }
}

// ---------------- launcher ----------------------------------------------------
extern "C" void kernel_launch(void* const* d_in, const int* in_sizes, int n_in,
                              void* d_out, int out_size, void* d_ws, size_t ws_size,
                              hipStream_t stream) {
  const float* x   = (const float*)d_in[0];
  const float* gsc = (const float*)d_in[1];
  const float* gbi = (const float*)d_in[2];
  const float* wq  = (const float*)d_in[3];
  const float* bq  = (const float*)d_in[4];
  const float* wk  = (const float*)d_in[5];
  const float* bk  = (const float*)d_in[6];
  const float* wv  = (const float*)d_in[7];
  const float* bv  = (const float*)d_in[8];
  const float* wp  = (const float*)d_in[9];
  const float* bp  = (const float*)d_in[10];
  float* out = (float*)d_out;

  char* ws = (char*)d_ws;
  u16*   wqkv  = (u16*)(ws + 0);         // 768*256 bf16
  u16*   wpb   = (u16*)(ws + 393216);    // 256*256 bf16
  float* bqkv  = (float*)(ws + 524288);  // 768 f32
  float* stats = (float*)(ws + 527360);  // 128*2 f32
  u16*   hnT   = (u16*)(ws + 1048576);   // 4*4096*256 bf16; reused as OT after QKV
  u16*   qT    = (u16*)(ws + 9437184);
  u16*   kT    = (u16*)(ws + 17825792);
  u16*   vv    = (u16*)(ws + 26214400);  // end: 34,603,008 bytes

  k_conv<<<256, 256, 0, stream>>>(wq, wk, wv, wp, bq, bk, bv, wqkv, wpb, bqkv);
  k_stats<<<128, 256, 0, stream>>>(x, stats);
  k_apply<<<dim3(64, 4), 256, 0, stream>>>(x, stats, gsc, gbi, hnT);
  k_qkv<<<dim3(64, 12, 4), 256, 0, stream>>>(wqkv, bqkv, hnT, qT, kT, vv);
  k_flash<<<256, 256, 0, stream>>>(qT, kT, vv, hnT /*OT*/);
  k_proj<<<dim3(64, 4, 4), 256, 0, stream>>>(wpb, bp, hnT /*OT*/, x, out);
}

// Round 2
// 258.375 us; speedup vs baseline: 1.4397x; 1.4397x over previous
//
#include <hip/hip_runtime.h>
#include <stdint.h>

#define Bn 4
#define Cn 256
#define Gn 32
#define Nn 4096
#define CGn 8

typedef unsigned short u16;
typedef __attribute__((ext_vector_type(8))) short short8;
typedef __attribute__((ext_vector_type(4))) short short4v;
typedef __attribute__((ext_vector_type(4))) float f32x4;

__device__ __forceinline__ u16 f2bf(float x) {
  uint32_t u = __float_as_uint(x);
  u += 0x7fffu + ((u >> 16) & 1u);
  return (u16)(u >> 16);
}
__device__ __forceinline__ float b2f(u16 v) {
  return __uint_as_float(((uint32_t)v) << 16);
}

// async global->LDS, 16B per lane; lds base must be wave-uniform
__device__ __forceinline__ void gl_lds16(const void* g, void* l) {
  __builtin_amdgcn_global_load_lds(
      (__attribute__((address_space(1))) void*)(uintptr_t)g,
      (__attribute__((address_space(3))) void*)(uintptr_t)l, 16, 0, 0);
}

// XOR-swizzled tile addressing: rows of 512B (32 x 16B chunks) / 128B (8 chunks).
// physical chunk = logical chunk ^ (row & 7)  (involution)
__device__ __forceinline__ int sw512(int row, int cb) { return row * 512 + ((cb ^ (row & 7)) * 16); }
__device__ __forceinline__ int sw128(int row, int cb) { return row * 128 + ((cb ^ (row & 7)) * 16); }

// ---------------- weight convert: fp32 -> bf16, fold log2(e)/16 into wq,bq ----
__global__ void k_conv(const float* __restrict__ wq, const float* __restrict__ wk,
                       const float* __restrict__ wv, const float* __restrict__ wp,
                       const float* __restrict__ bq, const float* __restrict__ bk,
                       const float* __restrict__ bv,
                       u16* __restrict__ wqkv, u16* __restrict__ wpb, float* __restrict__ bqkv) {
  const float s = 0.09016844005556021f;  // log2(e) / sqrt(256)
  int i = blockIdx.x * 256 + threadIdx.x;  // grid 256 -> 65536 threads
  wqkv[i]          = f2bf(wq[i] * s);
  wqkv[i + 65536]  = f2bf(wk[i]);
  wqkv[i + 131072] = f2bf(wv[i]);
  wpb[i]           = f2bf(wp[i]);
  if (i < 256) { bqkv[i] = bq[i] * s; bqkv[i + 256] = bk[i]; bqkv[i + 512] = bv[i]; }
}

// ---------------- GroupNorm stats: 4 blocks per (b,g), atomic accumulate -----
__global__ void k_stats(const float* __restrict__ x, float* __restrict__ stats) {
  int blk = blockIdx.x;           // (b*32+g)*4 + part
  int grp = blk >> 2, part = blk & 3;
  const float4* base = (const float4*)(x + (size_t)grp * (CGn * Nn) + part * 8192);
  float s = 0.f, s2 = 0.f;
  for (int i = threadIdx.x; i < 2048; i += 256) {
    float4 v = base[i];
    s  += v.x + v.y + v.z + v.w;
    s2 += v.x * v.x + v.y * v.y + v.z * v.z + v.w * v.w;
  }
#pragma unroll
  for (int m = 1; m < 64; m <<= 1) { s += __shfl_xor(s, m, 64); s2 += __shfl_xor(s2, m, 64); }
  __shared__ float ps[4], ps2[4];
  int w = threadIdx.x >> 6;
  if ((threadIdx.x & 63) == 0) { ps[w] = s; ps2[w] = s2; }
  __syncthreads();
  if (threadIdx.x == 0) {
    atomicAdd(&stats[grp * 2], ps[0] + ps[1] + ps[2] + ps[3]);
    atomicAdd(&stats[grp * 2 + 1], ps2[0] + ps2[1] + ps2[2] + ps2[3]);
  }
}

// ---------------- GN apply -> hnT (N,C) bf16 ---------------------------------
__global__ void k_apply(const float* __restrict__ x, const float* __restrict__ stats,
                        const float* __restrict__ gsc, const float* __restrict__ gbi,
                        u16* __restrict__ hnT) {
  int n0 = blockIdx.x * 64;
  int b = blockIdx.y;
  int tid = threadIdx.x;
  __shared__ float smu[Gn], srs[Gn];
  if (tid < Gn) {
    float S = stats[(b * Gn + tid) * 2], S2 = stats[(b * Gn + tid) * 2 + 1];
    const float inv = 1.f / (CGn * Nn);
    float mu = S * inv;
    float var = S2 * inv - mu * mu;
    smu[tid] = mu;
    srs[tid] = rsqrtf(var + 1e-6f);
  }
  __syncthreads();
  int nl = (tid & 15) * 4;
  int cbase = tid >> 4;
  for (int pass = 0; pass < 16; ++pass) {
    int c = pass * 16 + cbase;
    float4 v = *(const float4*)(x + (size_t)b * Cn * Nn + (size_t)c * Nn + n0 + nl);
    int g = c >> 3;
    float sc = gsc[c] * srs[g];
    float bi = gbi[c] - smu[g] * sc;
    u16* dst = hnT + (size_t)b * Nn * Cn + (size_t)(n0 + nl) * Cn + c;
    dst[0]      = f2bf(v.x * sc + bi);
    dst[Cn]     = f2bf(v.y * sc + bi);
    dst[2 * Cn] = f2bf(v.z * sc + bi);
    dst[3 * Cn] = f2bf(v.w * sc + bi);
  }
}

// ---------------- fused QKV GEMM: out[d,n] = sum_c W[d,c] hn[c,n] + bias ------
// q,k stored transposed (N,C); v stored (C,N)
__global__ __launch_bounds__(256, 2)
void k_qkv(const u16* __restrict__ wqkv, const float* __restrict__ bqkv,
           const u16* __restrict__ hnT, u16* __restrict__ qT, u16* __restrict__ kT,
           u16* __restrict__ vv) {
  __shared__ __align__(16) char smem[65536];  // Ws [64][512B sw] | hns [64][512B sw]
  int tid = threadIdx.x, lane = tid & 63, w = tid >> 6, quad = lane >> 4, low = lane & 15;
  int n0 = blockIdx.x * 64, d0 = blockIdx.y * 64, b = blockIdx.z;
  {
    int r0 = w * 16;
#pragma unroll
    for (int s = 0; s < 8; ++s) {
      int rs = r0 + s * 2;
      int r = rs + (lane >> 5);
      int cb = (lane & 31) ^ (r & 7);
      gl_lds16(wqkv + (size_t)(d0 + r) * Cn + cb * 8, smem + rs * 512);
      gl_lds16(hnT + ((size_t)b * Nn + n0 + r) * Cn + cb * 8, smem + 32768 + rs * 512);
    }
  }
  asm volatile("s_waitcnt vmcnt(0)" ::: "memory");
  __syncthreads();
  f32x4 acc[4] = {{0.f,0.f,0.f,0.f},{0.f,0.f,0.f,0.f},{0.f,0.f,0.f,0.f},{0.f,0.f,0.f,0.f}};
#pragma unroll
  for (int kk = 0; kk < 8; ++kk) {
    short8 af = *(const short8*)(smem + sw512(w * 16 + low, kk * 4 + quad));
#pragma unroll
    for (int t = 0; t < 4; ++t) {
      short8 bf = *(const short8*)(smem + 32768 + sw512(t * 16 + low, kk * 4 + quad));
      acc[t] = __builtin_amdgcn_mfma_f32_16x16x32_bf16(af, bf, acc[t], 0, 0, 0);
    }
  }
  int which = d0 >> 8;
  int dloc = (d0 & 255) + w * 16 + quad * 4;
  float bias[4];
#pragma unroll
  for (int r = 0; r < 4; ++r) bias[r] = bqkv[d0 + w * 16 + quad * 4 + r];
  if (which == 2) {
    u16* vp = vv + (size_t)b * Cn * Nn;
#pragma unroll
    for (int t = 0; t < 4; ++t)
#pragma unroll
      for (int r = 0; r < 4; ++r)
        vp[(size_t)(dloc + r) * Nn + n0 + t * 16 + low] = f2bf(acc[t][r] + bias[r]);
  } else {
    u16* dst = (which == 0 ? qT : kT) + (size_t)b * Nn * Cn;
#pragma unroll
    for (int t = 0; t < 4; ++t) {
      short4v pk;
#pragma unroll
      for (int r = 0; r < 4; ++r) pk[r] = (short)f2bf(acc[t][r] + bias[r]);
      *(short4v*)(dst + (size_t)(n0 + t * 16 + low) * Cn + dloc) = pk;
    }
  }
}

// ---------------- flash attention, KV split 2-way for 2 blocks/CU ------------
// each block: 64 q-rows x 2048 kv-cols, writes unnormalized partial O (bf16,
// C-layout (N,C)) + per-row (m, l) in log2 domain
__global__ __launch_bounds__(256, 2)
void k_flash(const u16* __restrict__ qT, const u16* __restrict__ kT,
             const u16* __restrict__ vv, u16* __restrict__ Op0,
             u16* __restrict__ Op1, float2* __restrict__ ml) {
  __shared__ __align__(16) char smem[65536];  // ks [64][512B sw] | vs [256][128B sw]
  const int tid = threadIdx.x, lane = tid & 63, w = tid >> 6, quad = lane >> 4, low = lane & 15;
  const int i0 = blockIdx.x * 64;
  const int b = blockIdx.y;
  const int jh = blockIdx.z;
  const u16* qTb = qT + (size_t)b * Nn * Cn;
  const u16* kTb = kT + (size_t)b * Nn * Cn;
  const u16* vb  = vv + (size_t)b * Cn * Nn;

  // q A-fragments for this wave's 16 rows, held in registers (full K=256)
  short8 qf[8];
  {
    const u16* qrow = qTb + (size_t)(i0 + w * 16 + low) * Cn;
#pragma unroll
    for (int kk = 0; kk < 8; ++kk) qf[kk] = *(const short8*)(qrow + kk * 32 + quad * 8);
  }
  f32x4 O[16];
#pragma unroll
  for (int t = 0; t < 16; ++t) O[t] = (f32x4){0.f, 0.f, 0.f, 0.f};
  float m_[4], l_[4];
#pragma unroll
  for (int r = 0; r < 4; ++r) { m_[r] = -1e30f; l_[r] = 0.f; }

  for (int jt = 0; jt < 32; ++jt) {
    const int j0 = jh * 2048 + jt * 64;
    __syncthreads();  // everyone done reading prev ks/vs/P
    {
      int r0 = w * 16;
#pragma unroll
      for (int s = 0; s < 8; ++s) {  // ks: 64 rows x 512B from kT rows j0+r
        int rs = r0 + s * 2;
        int r = rs + (lane >> 5);
        int cb = (lane & 31) ^ (r & 7);
        gl_lds16(kTb + (size_t)(j0 + r) * Cn + cb * 8, smem + rs * 512);
      }
      int c0 = w * 64;
#pragma unroll
      for (int s = 0; s < 8; ++s) {  // vs: 256 rows x 128B from v rows, col j0
        int rs = c0 + s * 8;
        int r = rs + (lane >> 3);
        int cb = (lane & 7) ^ (r & 7);
        gl_lds16(vb + (size_t)r * Nn + j0 + cb * 8, smem + 32768 + rs * 128);
      }
    }
    asm volatile("s_waitcnt vmcnt(0)" ::: "memory");
    __syncthreads();

    // S = q^T k  (wave: 16 rows x 64 cols, log2-domain logits)
    f32x4 S4[4] = {{0.f,0.f,0.f,0.f},{0.f,0.f,0.f,0.f},{0.f,0.f,0.f,0.f},{0.f,0.f,0.f,0.f}};
#pragma unroll
    for (int kk = 0; kk < 8; ++kk) {
#pragma unroll
      for (int t = 0; t < 4; ++t) {
        short8 bf = *(const short8*)(smem + sw512(t * 16 + low, kk * 4 + quad));
        S4[t] = __builtin_amdgcn_mfma_f32_16x16x32_bf16(qf[kk], bf, S4[t], 0, 0, 0);
      }
    }
    __syncthreads();  // all waves done reading ks; safe to reuse ks region for P

    // online softmax; rows r: global row = i0 + w*16 + quad*4 + r
    float alpha[4];
#pragma unroll
    for (int r = 0; r < 4; ++r) {
      float v0 = fmaxf(fmaxf(S4[0][r], S4[1][r]), fmaxf(S4[2][r], S4[3][r]));
#pragma unroll
      for (int msk = 1; msk < 16; msk <<= 1) v0 = fmaxf(v0, __shfl_xor(v0, msk, 64));
      float mn = fmaxf(m_[r], v0);
      alpha[r] = __builtin_amdgcn_exp2f(m_[r] - mn);
      m_[r] = mn;
    }
    float Pv[4][4], rsum[4] = {0.f, 0.f, 0.f, 0.f};
#pragma unroll
    for (int t = 0; t < 4; ++t)
#pragma unroll
      for (int r = 0; r < 4; ++r) {
        float p = __builtin_amdgcn_exp2f(S4[t][r] - m_[r]);
        Pv[t][r] = p;
        rsum[r] += p;
      }
#pragma unroll
    for (int r = 0; r < 4; ++r) {
      float s0 = rsum[r];
#pragma unroll
      for (int msk = 1; msk < 16; msk <<= 1) s0 += __shfl_xor(s0, msk, 64);
      l_[r] = l_[r] * alpha[r] + s0;
    }
#pragma unroll
    for (int t = 0; t < 16; ++t)
#pragma unroll
      for (int r = 0; r < 4; ++r) O[t][r] *= alpha[r];
    // write P (16 x 64 bf16) to this wave's quarter of the ks region.
    // row-hash (mrow>>1)&7: per-(t,r) store the 64 lanes spread over all 8
    // chunk-groups -> 2 lanes/bank (free), vs 4-way with (mrow&7)
#pragma unroll
    for (int t = 0; t < 4; ++t)
#pragma unroll
      for (int r = 0; r < 4; ++r) {
        int mrow = quad * 4 + r;
        int col = t * 16 + low;
        int off = w * 8192 + mrow * 128 + ((((col >> 3) ^ ((mrow >> 1) & 7)) & 7) * 16) + (col & 7) * 2;
        *(u16*)(smem + off) = f2bf(Pv[t][r]);
      }
    // O += P @ V^T
#pragma unroll
    for (int kk2 = 0; kk2 < 2; ++kk2) {
      short8 af = *(const short8*)(smem + w * 8192 + low * 128 +
                                   ((((kk2 * 4 + quad) ^ ((low >> 1) & 7)) & 7) * 16));
#pragma unroll
      for (int t = 0; t < 16; ++t) {
        short8 bf = *(const short8*)(smem + 32768 + sw128(t * 16 + low, kk2 * 4 + quad));
        O[t] = __builtin_amdgcn_mfma_f32_16x16x32_bf16(af, bf, O[t], 0, 0, 0);
      }
    }
  }

  // epilogue: unnormalized partial O -> bf16 global (C-layout), plus (m,l)
  u16* Ob = (jh ? Op1 : Op0) + ((size_t)b * Nn + i0 + w * 16) * (size_t)Cn;
#pragma unroll
  for (int t = 0; t < 16; ++t)
#pragma unroll
    for (int r = 0; r < 4; ++r)
      Ob[(size_t)(quad * 4 + r) * Cn + t * 16 + low] = f2bf(O[t][r]);
  if (low == 0) {
#pragma unroll
    for (int r = 0; r < 4; ++r)
      ml[(size_t)jh * (Bn * Nn) + (size_t)b * Nn + i0 + w * 16 + quad * 4 + r] =
          make_float2(m_[r], l_[r]);
  }
}

// ---------------- combine the two KV halves -> OT (N,C) bf16 -----------------
__global__ void k_comb(const u16* __restrict__ O0, const u16* __restrict__ O1,
                       const float2* __restrict__ ml, u16* __restrict__ OT) {
  int gid = blockIdx.x * 256 + threadIdx.x;  // 1M threads, 4 cols each
  int row = gid >> 6;
  int c4 = (gid & 63) << 2;
  float2 e0 = ml[row];
  float2 e1 = ml[Bn * Nn + row];
  float M = fmaxf(e0.x, e1.x);
  float w0 = __builtin_amdgcn_exp2f(e0.x - M);
  float w1 = __builtin_amdgcn_exp2f(e1.x - M);
  float inv = __builtin_amdgcn_rcpf(e0.y * w0 + e1.y * w1);
  w0 *= inv; w1 *= inv;
  short4v a0 = *(const short4v*)(O0 + (size_t)row * Cn + c4);
  short4v a1 = *(const short4v*)(O1 + (size_t)row * Cn + c4);
  short4v o;
#pragma unroll
  for (int i = 0; i < 4; ++i)
    o[i] = (short)f2bf(b2f((u16)a0[i]) * w0 + b2f((u16)a1[i]) * w1);
  *(short4v*)(OT + (size_t)row * Cn + c4) = o;
}

// ---------------- proj GEMM + bias + residual --------------------------------
__global__ __launch_bounds__(256, 2)
void k_proj(const u16* __restrict__ wpb, const float* __restrict__ bp,
            const u16* __restrict__ OT, const float* __restrict__ x,
            float* __restrict__ out) {
  __shared__ __align__(16) char smem[65536];
  int tid = threadIdx.x, lane = tid & 63, w = tid >> 6, quad = lane >> 4, low = lane & 15;
  int n0 = blockIdx.x * 64, d0 = blockIdx.y * 64, b = blockIdx.z;
  {
    int r0 = w * 16;
#pragma unroll
    for (int s = 0; s < 8; ++s) {
      int rs = r0 + s * 2;
      int r = rs + (lane >> 5);
      int cb = (lane & 31) ^ (r & 7);
      gl_lds16(wpb + (size_t)(d0 + r) * Cn + cb * 8, smem + rs * 512);
      gl_lds16(OT + ((size_t)b * Nn + n0 + r) * Cn + cb * 8, smem + 32768 + rs * 512);
    }
  }
  asm volatile("s_waitcnt vmcnt(0)" ::: "memory");
  __syncthreads();
  f32x4 acc[4] = {{0.f,0.f,0.f,0.f},{0.f,0.f,0.f,0.f},{0.f,0.f,0.f,0.f},{0.f,0.f,0.f,0.f}};
#pragma unroll
  for (int kk = 0; kk < 8; ++kk) {
    short8 af = *(const short8*)(smem + sw512(w * 16 + low, kk * 4 + quad));
#pragma unroll
    for (int t = 0; t < 4; ++t) {
      short8 bf = *(const short8*)(smem + 32768 + sw512(t * 16 + low, kk * 4 + quad));
      acc[t] = __builtin_amdgcn_mfma_f32_16x16x32_bf16(af, bf, acc[t], 0, 0, 0);
    }
  }
  int dloc = d0 + w * 16 + quad * 4;
#pragma unroll
  for (int t = 0; t < 4; ++t)
#pragma unroll
    for (int r = 0; r < 4; ++r) {
      size_t idx = (size_t)b * Cn * Nn + (size_t)(dloc + r) * Nn + n0 + t * 16 + low;
      out[idx] = x[idx] + acc[t][r] + bp[dloc + r];
    }
}

// ---------------- launcher ----------------------------------------------------
extern "C" void kernel_launch(void* const* d_in, const int* in_sizes, int n_in,
                              void* d_out, int out_size, void* d_ws, size_t ws_size,
                              hipStream_t stream) {
  const float* x   = (const float*)d_in[0];
  const float* gsc = (const float*)d_in[1];
  const float* gbi = (const float*)d_in[2];
  const float* wq  = (const float*)d_in[3];
  const float* bq  = (const float*)d_in[4];
  const float* wk  = (const float*)d_in[5];
  const float* bk  = (const float*)d_in[6];
  const float* wv  = (const float*)d_in[7];
  const float* bv  = (const float*)d_in[8];
  const float* wp  = (const float*)d_in[9];
  const float* bp  = (const float*)d_in[10];
  float* out = (float*)d_out;

  char* ws = (char*)d_ws;
  u16*   wqkv  = (u16*)(ws + 0);          // 768*256 bf16
  u16*   wpb   = (u16*)(ws + 393216);     // 256*256 bf16
  float* bqkv  = (float*)(ws + 524288);   // 768 f32
  float* stats = (float*)(ws + 527360);   // 128*2 f32 (atomic-accumulated)
  u16*   hnT   = (u16*)(ws + 1048576);    // 8 MB; reused as Opart half0 after qkv
  u16*   qT    = (u16*)(ws + 9437184);    // 8 MB; reused as OT after flash
  u16*   kT    = (u16*)(ws + 17825792);   // 8 MB
  u16*   vv    = (u16*)(ws + 26214400);   // 8 MB
  u16*   Op1   = (u16*)(ws + 34603008);   // 8 MB  (Opart half1)
  float2* mlp  = (float2*)(ws + 42991616);// 32768*8 B; end ~43.3 MB

  hipMemsetAsync(stats, 0, 1024, stream);
  k_conv<<<256, 256, 0, stream>>>(wq, wk, wv, wp, bq, bk, bv, wqkv, wpb, bqkv);
  k_stats<<<512, 256, 0, stream>>>(x, stats);
  k_apply<<<dim3(64, 4), 256, 0, stream>>>(x, stats, gsc, gbi, hnT);
  k_qkv<<<dim3(64, 12, 4), 256, 0, stream>>>(wqkv, bqkv, hnT, qT, kT, vv);
  k_flash<<<dim3(64, 4, 2), 256, 0, stream>>>(qT, kT, vv, hnT /*Op0*/, Op1, mlp);
  k_comb<<<4096, 256, 0, stream>>>(hnT, Op1, mlp, qT /*OT*/);
  k_proj<<<dim3(64, 4, 4), 256, 0, stream>>>(wpb, bp, qT /*OT*/, x, out);
}